// Round 10
// baseline (96.518 us; speedup 1.0000x reference)
//
#include <hip/hip_runtime.h>
#include <math.h>

#define EPS 1e-6f
#define IPB 4    // i per block (amortizes the j-stream)

struct F3 { float x, y, z; };
__device__ inline F3 sub3(F3 a, F3 b){return {a.x-b.x,a.y-b.y,a.z-b.z};}
__device__ inline float dot3(F3 a, F3 b){return a.x*b.x+a.y*b.y+a.z*b.z;}
__device__ inline F3 scale3(F3 a,float s){return {a.x*s,a.y*s,a.z*s};}
__device__ inline F3 cross3(F3 a,F3 b){return {a.y*b.z-a.z*b.y, a.z*b.x-a.x*b.z, a.x*b.y-a.y*b.x};}
__device__ inline F3 norm3(F3 v){float s=dot3(v,v);float inv=1.f/sqrtf(fmaxf(s,EPS));return scale3(v,inv);}

__device__ inline void make_frame(const float* __restrict__ base, float R[9], F3& ca) {
    F3 n = {base[0], base[1], base[2]};
    ca   = {base[3], base[4], base[5]};
    F3 c = {base[6], base[7], base[8]};
    F3 e1 = norm3(sub3(c, ca));
    F3 v2 = sub3(n, ca);
    float d = dot3(e1, v2);
    F3 e2 = norm3({v2.x - d*e1.x, v2.y - d*e1.y, v2.z - d*e1.z});
    F3 e3 = cross3(e1, e2);
    R[0]=e1.x; R[1]=e1.y; R[2]=e1.z;
    R[3]=e2.x; R[4]=e2.y; R[5]=e2.z;
    R[6]=e3.x; R[7]=e3.y; R[8]=e3.z;
}

// ---------------- prep + transpose fused ----------------
__global__ __launch_bounds__(256) void prep_all_kernel(
    const float* __restrict__ pred, const float* __restrict__ gt,
    const float* __restrict__ atom_mask, const int* __restrict__ batch,
    const int* __restrict__ chain,
    float* __restrict__ Mc, int* __restrict__ packed,
    float* __restrict__ gtca, float* __restrict__ predca,
    float4* __restrict__ predT4, float4* __restrict__ gtT4,
    int L, int N, int A)
{
    int idx = blockIdx.x * blockDim.x + threadIdx.x;

    // ---- transpose part: float4 slabs [a][j] ----
    int totalT = (L + 1) * A * N;
    if (idx < totalT) {
        int z = idx / (A * N);
        int r = idx - z * (A * N);
        int a = r / N;
        int j = r - a * N;
        if (z < L) {
            const float* s = pred + (((size_t)z * N + j) * A + a) * 3;
            predT4[((size_t)z * A + a) * N + j] = make_float4(s[0], s[1], s[2], 0.f);
        } else {
            const float* s = gt + ((size_t)j * A + a) * 3;
            gtT4[(size_t)a * N + j] = make_float4(s[0], s[1], s[2], 0.f);
        }
    }

    // ---- prep part ----
    if (idx >= L * N) return;
    int l = idx / N, i = idx - l * N;

    float Rg[9]; F3 cag;
    make_frame(gt + (size_t)i * A * 3, Rg, cag);
    float Rp[9]; F3 cap;
    make_frame(pred + ((size_t)l * N + i) * A * 3, Rp, cap);

    // |Rp^T(x-tp) - Rg^T(y-tg)| == |x - (M y + c)|, M = Rp Rg^T, c = tp - M tg
    float m[9];
    #pragma unroll
    for (int d = 0; d < 3; d++)
        #pragma unroll
        for (int e = 0; e < 3; e++)
            m[d*3+e] = Rp[0*3+d]*Rg[0*3+e] + Rp[1*3+d]*Rg[1*3+e] + Rp[2*3+d]*Rg[2*3+e];
    float c0 = cap.x - (m[0]*cag.x + m[1]*cag.y + m[2]*cag.z);
    float c1 = cap.y - (m[3]*cag.x + m[4]*cag.y + m[5]*cag.z);
    float c2 = cap.z - (m[6]*cag.x + m[7]*cag.y + m[8]*cag.z);

    float* o = Mc + (size_t)idx * 12;
    #pragma unroll
    for (int k = 0; k < 9; k++) o[k] = m[k];
    o[9] = c0; o[10] = c1; o[11] = c2;

    if (l == 0) {
        unsigned mm = 0;
        for (int a = 0; a < A; a++)
            if (atom_mask[(size_t)i * A + a] > 0.f) mm |= (1u << a);
        packed[i] = (int)(mm | ((unsigned)batch[i] << 16) | ((unsigned)chain[i] << 24));
        gtca[i*3] = cag.x; gtca[i*3+1] = cag.y; gtca[i*3+2] = cag.z;
    }
    if (l == L - 1) { predca[i*3] = cap.x; predca[i*3+1] = cap.y; predca[i*3+2] = cap.z; }
}

// ---------------- fape: block = (l, 4 i's), lanes stride j; float4 SoA loads ----
// All per-i state (M, c, masks, CA) is block-uniform -> SGPRs; the j-stream
// (28 dwordx4/iter) is read once and reused for 4 i's.
__global__ __launch_bounds__(256) void fape_kernel(
    const float4* __restrict__ predT4, const float4* __restrict__ gtT4,
    const float* __restrict__ Mc, const int* __restrict__ packed,
    const float* __restrict__ gtca, const float* __restrict__ predca,
    float* __restrict__ part,
    float* __restrict__ out_final, float* __restrict__ out_rot,
    float* __restrict__ out_lddt,
    int L, int N)
{
    int t = threadIdx.x;
    int ib = blockIdx.x, l = blockIdx.y;
    int i0 = ib * IPB;
    bool last = (l == L - 1);

    // block-uniform per-i state -> scalar loads
    float M[IPB][12];
    int msk[IPB], bat[IPB], chn[IPB];
    float gx[IPB], gy[IPB], gz[IPB], px[IPB], py[IPB], pz[IPB];
    #pragma unroll
    for (int q = 0; q < IPB; q++) {
        int i = i0 + q;
        const float* __restrict__ mcp = Mc + ((size_t)l * N + i) * 12;
        #pragma unroll
        for (int k = 0; k < 12; k++) M[q][k] = mcp[k];
        int pk = packed[i];
        msk[q] = pk & 0xFFFF; bat[q] = (pk >> 16) & 0xFF; chn[q] = (pk >> 24) & 0xFF;
        if (last) {
            gx[q]=gtca[i*3]; gy[q]=gtca[i*3+1]; gz[q]=gtca[i*3+2];
            px[q]=predca[i*3]; py[q]=predca[i*3+1]; pz[q]=predca[i*3+2];
        } else { gx[q]=gy[q]=gz[q]=px[q]=py[q]=pz[q]=0.f; }
    }

    const float4* __restrict__ xT4 = predT4 + (size_t)l * 14 * N;   // [a][j]

    float a_ss=0.f, a_so=0.f, a_cs=0.f, a_co=0.f, a_rot=0.f;
    float ls[IPB], lc[IPB];
    #pragma unroll
    for (int q = 0; q < IPB; q++) { ls[q]=0.f; lc[q]=0.f; }

    for (int j = t; j < N; j += 256) {
        int pkj = packed[j];
        int mskj = pkj & 0xFFFF;
        int bj = (pkj >> 16) & 0xFF, cj = (pkj >> 24) & 0xFF;

        int mj[IPB]; bool pm[IPB];
        bool anypm = false;
        #pragma unroll
        for (int q = 0; q < IPB; q++) {
            mj[q] = msk[q] & mskj;
            pm[q] = (bj == bat[q]) && (mj[q] != 0);
            anypm |= pm[q];
        }
        float num[IPB];
        #pragma unroll
        for (int q = 0; q < IPB; q++) num[q] = 0.f;

        if (__any(anypm)) {
            #pragma unroll
            for (int a = 0; a < 14; a++) {
                float4 Y = gtT4[(size_t)a * N + j];   // coalesced dwordx4, shared by 4 i's
                float4 X = xT4[(size_t)a * N + j];
                #pragma unroll
                for (int q = 0; q < IPB; q++) {
                    float d0 = X.x - (M[q][0]*Y.x + M[q][1]*Y.y + M[q][2]*Y.z + M[q][9]);
                    float d1 = X.y - (M[q][3]*Y.x + M[q][4]*Y.y + M[q][5]*Y.z + M[q][10]);
                    float d2 = X.z - (M[q][6]*Y.x + M[q][7]*Y.y + M[q][8]*Y.z + M[q][11]);
                    num[q] += (float)((mj[q] >> a) & 1) * sqrtf(fmaxf(d0*d0+d1*d1+d2*d2, EPS));
                }
            }
        }

        float4 CG, CP;
        if (last) { CG = gtT4[(size_t)1 * N + j]; CP = xT4[(size_t)1 * N + j]; }

        #pragma unroll
        for (int q = 0; q < IPB; q++) {
            int i = i0 + q;
            float fv = pm[q] ? num[q] / (float)__popc((unsigned)mj[q]) : 0.f;
            if (last) {
                out_final[(size_t)i * N + j] = fv;   // coalesced
                if (j == i) out_rot[i] = fv;
            }
            if (j == i) a_rot += fv;
            if (pm[q]) {
                float cl = fminf(fv, 10.f);
                if (chn[q] == cj) { a_ss += cl; a_cs += 1.f; } else { a_so += cl; a_co += 1.f; }
            }
            if (last) {
                bool ok = (msk[q] != 0) && (mskj != 0) && (j != i);
                if (ok) {
                    float dx=gx[q]-CG.x, dy=gy[q]-CG.y, dz=gz[q]-CG.z;
                    float gd = sqrtf(fmaxf(dx*dx+dy*dy+dz*dz, EPS));
                    if (gd < 15.f) {
                        float ex=px[q]-CP.x, ey=py[q]-CP.y, ez=pz[q]-CP.z;
                        float pd = sqrtf(fmaxf(ex*ex+ey*ey+ez*ez, EPS));
                        float de = fabsf(gd - pd);
                        ls[q] += ((de<0.5f?1.f:0.f)+(de<1.f?1.f:0.f)+(de<2.f?1.f:0.f)+(de<4.f?1.f:0.f))*0.25f;
                        lc[q] += 1.f;
                    }
                }
            }
        }
    }

    // ---- block-local reduction of 5 + 2*IPB values (no global atomics) ----
    float vals[5 + 2*IPB];
    vals[0]=a_ss; vals[1]=a_so; vals[2]=a_cs; vals[3]=a_co; vals[4]=a_rot;
    #pragma unroll
    for (int q = 0; q < IPB; q++) { vals[5+2*q]=ls[q]; vals[6+2*q]=lc[q]; }
    #pragma unroll
    for (int k = 0; k < 5 + 2*IPB; k++)
        for (int o = 32; o > 0; o >>= 1) vals[k] += __shfl_down(vals[k], o, 64);

    __shared__ float red[4][5 + 2*IPB];
    int wave = t >> 6, lane = t & 63;
    if (lane == 0) {
        #pragma unroll
        for (int k = 0; k < 5 + 2*IPB; k++) red[wave][k] = vals[k];
    }
    __syncthreads();
    if (t == 0) {
        float v[5 + 2*IPB];
        #pragma unroll
        for (int k = 0; k < 5 + 2*IPB; k++)
            v[k] = red[0][k] + red[1][k] + red[2][k] + red[3][k];
        float* p = part + ((size_t)l * (N / IPB) + ib) * 8;
        p[0]=v[0]; p[1]=v[1]; p[2]=v[2]; p[3]=v[3]; p[4]=v[4];
        if (last) {
            #pragma unroll
            for (int q = 0; q < IPB; q++)
                out_lddt[i0 + q] = v[5+2*q] / fmaxf(v[6+2*q], 1e-6f);
        }
    }
}

// ---------------- reduce: sum per-block partials -> scalars ----------------
__global__ __launch_bounds__(256) void reduce_kernel(
    const int* __restrict__ packed, const float* __restrict__ part,
    float* __restrict__ out, int L, int N)
{
    int t = threadIdx.x;
    int BPL = N / IPB;
    float ss[4]={0,0,0,0}, so[4]={0,0,0,0}, rt[4]={0,0,0,0};
    float cs=0.f, co=0.f;
    for (int b = t; b < BPL * L; b += 256) {
        int l = b / BPL;
        const float* p = part + (size_t)b * 8;
        ss[l] += p[0]; so[l] += p[1]; rt[l] += p[4];
        if (l == 0) { cs += p[2]; co += p[3]; }
    }
    float nr = 0.f;
    for (int i = t; i < N; i += 256)
        nr += ((packed[i] & 0xFFFF) != 0) ? 1.f : 0.f;

    __shared__ float red[4];
    int wave = t >> 6, lane = t & 63;
    float vals[11];
    vals[0]=cs; vals[1]=co; vals[2]=nr;
    for (int l = 0; l < L; l++) { vals[3+l]=ss[l]; vals[3+L+l]=so[l]; vals[3+2*L+l]=rt[l]; }
    float res[11];
    for (int k = 0; k < 3 + 3*L; k++) {
        float v = vals[k];
        for (int o = 32; o > 0; o >>= 1) v += __shfl_down(v, o, 64);
        __syncthreads();
        if (lane == 0) red[wave] = v;
        __syncthreads();
        res[k] = red[0] + red[1] + red[2] + red[3];
    }
    if (t == 0) {
        float csf = fmaxf(res[0], 1e-6f);
        float cof = fmaxf(res[1], 1e-6f);
        float nrm = fmaxf(res[2], 1e-6f);
        for (int l = 0; l < L; l++) {
            out[l]     = res[3+l] / csf / 10.f + res[3+L+l] / cof / 10.f;
            out[L + l] = res[3+2*L+l] / nrm;
        }
    }
}

extern "C" void kernel_launch(void* const* d_in, const int* in_sizes, int n_in,
                              void* d_out, int out_size, void* d_ws, size_t ws_size,
                              hipStream_t stream)
{
    const float* pred      = (const float*)d_in[0];
    const float* gt        = (const float*)d_in[1];
    const float* atom_mask = (const float*)d_in[2];
    const int*   batch     = (const int*)d_in[3];
    const int*   chain     = (const int*)d_in[4];

    int N = in_sizes[3];
    int A = in_sizes[2] / N;
    int L = in_sizes[0] / (N * A * 3);

    float* out = (float*)d_out;
    float* out_final = out + 2 * L;
    float* out_rot   = out_final + (size_t)N * N;
    float* out_lddt  = out_rot + N;

    float* ws = (float*)d_ws;
    float* Mc      = ws;                                  // L*N*12
    float* gtca    = Mc + (size_t)L * N * 12;             // N*3
    float* predca  = gtca + (size_t)N * 3;                // N*3
    float* part    = predca + (size_t)N * 3;              // (L*N/IPB)*8
    float4* predT4 = (float4*)(part + (size_t)L * (N / IPB) * 8);  // L*A*N float4
    float4* gtT4   = predT4 + (size_t)L * A * N;          // A*N float4
    int*   packed  = (int*)(gtT4 + (size_t)A * N);        // N

    int totalT = (L + 1) * A * N;
    prep_all_kernel<<<(totalT + 255) / 256, 256, 0, stream>>>(
        pred, gt, atom_mask, batch, chain,
        Mc, packed, gtca, predca, predT4, gtT4, L, N, A);

    dim3 grid(N / IPB, L);   // 192 x 2 = 384 blocks
    fape_kernel<<<grid, 256, 0, stream>>>(
        predT4, gtT4, Mc, packed, gtca, predca, part,
        out_final, out_rot, out_lddt, L, N);

    reduce_kernel<<<1, 256, 0, stream>>>(packed, part, out, L, N);
}

// Round 11
// 95.494 us; speedup vs baseline: 1.0107x; 1.0107x over previous
//
#include <hip/hip_runtime.h>
#include <math.h>

#define EPS 1e-6f
#define IPB 4      // i per block
#define JSPLIT 3   // j chunks (N = JSPLIT*256)

struct F3 { float x, y, z; };
__device__ inline F3 sub3(F3 a, F3 b){return {a.x-b.x,a.y-b.y,a.z-b.z};}
__device__ inline float dot3(F3 a, F3 b){return a.x*b.x+a.y*b.y+a.z*b.z;}
__device__ inline F3 scale3(F3 a,float s){return {a.x*s,a.y*s,a.z*s};}
__device__ inline F3 cross3(F3 a,F3 b){return {a.y*b.z-a.z*b.y, a.z*b.x-a.x*b.z, a.x*b.y-a.y*b.x};}
__device__ inline F3 norm3(F3 v){float s=dot3(v,v);float inv=1.f/sqrtf(fmaxf(s,EPS));return scale3(v,inv);}

__device__ inline void make_frame(const float* __restrict__ base, float R[9], F3& ca) {
    F3 n = {base[0], base[1], base[2]};
    ca   = {base[3], base[4], base[5]};
    F3 c = {base[6], base[7], base[8]};
    F3 e1 = norm3(sub3(c, ca));
    F3 v2 = sub3(n, ca);
    float d = dot3(e1, v2);
    F3 e2 = norm3({v2.x - d*e1.x, v2.y - d*e1.y, v2.z - d*e1.z});
    F3 e3 = cross3(e1, e2);
    R[0]=e1.x; R[1]=e1.y; R[2]=e1.z;
    R[3]=e2.x; R[4]=e2.y; R[5]=e2.z;
    R[6]=e3.x; R[7]=e3.y; R[8]=e3.z;
}

// ---------------- prep + transpose fused ----------------
__global__ __launch_bounds__(256) void prep_all_kernel(
    const float* __restrict__ pred, const float* __restrict__ gt,
    const float* __restrict__ atom_mask, const int* __restrict__ batch,
    const int* __restrict__ chain,
    float* __restrict__ Mc, int* __restrict__ packed,
    float* __restrict__ gtca, float* __restrict__ predca,
    float4* __restrict__ predT4, float4* __restrict__ gtT4,
    int L, int N, int A)
{
    int idx = blockIdx.x * blockDim.x + threadIdx.x;

    // ---- transpose part: float4 slabs [a][j] ----
    int totalT = (L + 1) * A * N;
    if (idx < totalT) {
        int z = idx / (A * N);
        int r = idx - z * (A * N);
        int a = r / N;
        int j = r - a * N;
        if (z < L) {
            const float* s = pred + (((size_t)z * N + j) * A + a) * 3;
            predT4[((size_t)z * A + a) * N + j] = make_float4(s[0], s[1], s[2], 0.f);
        } else {
            const float* s = gt + ((size_t)j * A + a) * 3;
            gtT4[(size_t)a * N + j] = make_float4(s[0], s[1], s[2], 0.f);
        }
    }

    // ---- prep part ----
    if (idx >= L * N) return;
    int l = idx / N, i = idx - l * N;

    float Rg[9]; F3 cag;
    make_frame(gt + (size_t)i * A * 3, Rg, cag);
    float Rp[9]; F3 cap;
    make_frame(pred + ((size_t)l * N + i) * A * 3, Rp, cap);

    // |Rp^T(x-tp) - Rg^T(y-tg)| == |x - (M y + c)|, M = Rp Rg^T, c = tp - M tg
    float m[9];
    #pragma unroll
    for (int d = 0; d < 3; d++)
        #pragma unroll
        for (int e = 0; e < 3; e++)
            m[d*3+e] = Rp[0*3+d]*Rg[0*3+e] + Rp[1*3+d]*Rg[1*3+e] + Rp[2*3+d]*Rg[2*3+e];
    float c0 = cap.x - (m[0]*cag.x + m[1]*cag.y + m[2]*cag.z);
    float c1 = cap.y - (m[3]*cag.x + m[4]*cag.y + m[5]*cag.z);
    float c2 = cap.z - (m[6]*cag.x + m[7]*cag.y + m[8]*cag.z);

    float* o = Mc + (size_t)idx * 12;
    #pragma unroll
    for (int k = 0; k < 9; k++) o[k] = m[k];
    o[9] = c0; o[10] = c1; o[11] = c2;

    if (l == 0) {
        unsigned mm = 0;
        for (int a = 0; a < A; a++)
            if (atom_mask[(size_t)i * A + a] > 0.f) mm |= (1u << a);
        packed[i] = (int)(mm | ((unsigned)batch[i] << 16) | ((unsigned)chain[i] << 24));
        gtca[i*3] = cag.x; gtca[i*3+1] = cag.y; gtca[i*3+2] = cag.z;
    }
    if (l == L - 1) { predca[i*3] = cap.x; predca[i*3+1] = cap.y; predca[i*3+2] = cap.z; }
}

// ---------------- fape: block = (4 i's, j-chunk, l); thread owns ONE j ----
// Straight-line body, no j-loop. All reductions block-local; partials to part[]
// and lddt partial arrays (plain stores, distinct addresses, no atomics).
__global__ __launch_bounds__(256) void fape_kernel(
    const float4* __restrict__ predT4, const float4* __restrict__ gtT4,
    const float* __restrict__ Mc, const int* __restrict__ packed,
    const float* __restrict__ gtca, const float* __restrict__ predca,
    float* __restrict__ part,
    float* __restrict__ lddt_ls, float* __restrict__ lddt_lc,
    float* __restrict__ out_final, float* __restrict__ out_rot,
    float* __restrict__ out_lddt,
    int L, int N)
{
    int t = threadIdx.x;
    int ib = blockIdx.x, js = blockIdx.y, l = blockIdx.z;
    int i0 = ib * IPB;
    int j = js * 256 + t;
    bool last = (l == L - 1);

    // block-uniform per-i state -> scalar loads
    float M[IPB][12];
    int msk[IPB], bat[IPB], chn[IPB];
    float gx[IPB], gy[IPB], gz[IPB], px[IPB], py[IPB], pz[IPB];
    #pragma unroll
    for (int q = 0; q < IPB; q++) {
        int i = i0 + q;
        const float* __restrict__ mcp = Mc + ((size_t)l * N + i) * 12;
        #pragma unroll
        for (int k = 0; k < 12; k++) M[q][k] = mcp[k];
        int pk = packed[i];
        msk[q] = pk & 0xFFFF; bat[q] = (pk >> 16) & 0xFF; chn[q] = (pk >> 24) & 0xFF;
        if (last) {
            gx[q]=gtca[i*3]; gy[q]=gtca[i*3+1]; gz[q]=gtca[i*3+2];
            px[q]=predca[i*3]; py[q]=predca[i*3+1]; pz[q]=predca[i*3+2];
        } else { gx[q]=gy[q]=gz[q]=px[q]=py[q]=pz[q]=0.f; }
    }

    const float4* __restrict__ xT4 = predT4 + (size_t)l * 14 * N;   // [a][j]

    int pkj = packed[j];
    int mskj = pkj & 0xFFFF;
    int bj = (pkj >> 16) & 0xFF, cj = (pkj >> 24) & 0xFF;

    int mj[IPB]; bool pm[IPB];
    bool anypm = false;
    #pragma unroll
    for (int q = 0; q < IPB; q++) {
        mj[q] = msk[q] & mskj;
        pm[q] = (bj == bat[q]) && (mj[q] != 0);
        anypm |= pm[q];
    }
    float num[IPB];
    #pragma unroll
    for (int q = 0; q < IPB; q++) num[q] = 0.f;

    if (__any(anypm)) {
        #pragma unroll
        for (int a = 0; a < 14; a++) {
            float4 Y = gtT4[(size_t)a * N + j];   // coalesced dwordx4, shared by 4 i's
            float4 X = xT4[(size_t)a * N + j];
            #pragma unroll
            for (int q = 0; q < IPB; q++) {
                float d0 = X.x - (M[q][0]*Y.x + M[q][1]*Y.y + M[q][2]*Y.z + M[q][9]);
                float d1 = X.y - (M[q][3]*Y.x + M[q][4]*Y.y + M[q][5]*Y.z + M[q][10]);
                float d2 = X.z - (M[q][6]*Y.x + M[q][7]*Y.y + M[q][8]*Y.z + M[q][11]);
                num[q] += (float)((mj[q] >> a) & 1) * sqrtf(fmaxf(d0*d0+d1*d1+d2*d2, EPS));
            }
        }
    }

    float4 CG, CP;
    if (last) { CG = gtT4[(size_t)1 * N + j]; CP = xT4[(size_t)1 * N + j]; }

    float a_ss=0.f, a_so=0.f, a_cs=0.f, a_co=0.f, a_rot=0.f;
    float ls[IPB], lc[IPB];
    #pragma unroll
    for (int q = 0; q < IPB; q++) { ls[q]=0.f; lc[q]=0.f; }

    #pragma unroll
    for (int q = 0; q < IPB; q++) {
        int i = i0 + q;
        float fv = pm[q] ? num[q] / (float)__popc((unsigned)mj[q]) : 0.f;
        if (last) {
            out_final[(size_t)i * N + j] = fv;   // coalesced
            if (j == i) out_rot[i] = fv;
        }
        if (j == i) a_rot += fv;
        if (pm[q]) {
            float cl = fminf(fv, 10.f);
            if (chn[q] == cj) { a_ss += cl; a_cs += 1.f; } else { a_so += cl; a_co += 1.f; }
        }
        if (last) {
            bool ok = (msk[q] != 0) && (mskj != 0) && (j != i);
            if (ok) {
                float dx=gx[q]-CG.x, dy=gy[q]-CG.y, dz=gz[q]-CG.z;
                float gd = sqrtf(fmaxf(dx*dx+dy*dy+dz*dz, EPS));
                if (gd < 15.f) {
                    float ex=px[q]-CP.x, ey=py[q]-CP.y, ez=pz[q]-CP.z;
                    float pd = sqrtf(fmaxf(ex*ex+ey*ey+ez*ez, EPS));
                    float de = fabsf(gd - pd);
                    ls[q] += ((de<0.5f?1.f:0.f)+(de<1.f?1.f:0.f)+(de<2.f?1.f:0.f)+(de<4.f?1.f:0.f))*0.25f;
                    lc[q] += 1.f;
                }
            }
        }
    }

    // ---- block-local reduction of 5 + 2*IPB values ----
    float vals[5 + 2*IPB];
    vals[0]=a_ss; vals[1]=a_so; vals[2]=a_cs; vals[3]=a_co; vals[4]=a_rot;
    #pragma unroll
    for (int q = 0; q < IPB; q++) { vals[5+2*q]=ls[q]; vals[6+2*q]=lc[q]; }
    #pragma unroll
    for (int k = 0; k < 5 + 2*IPB; k++)
        for (int o = 32; o > 0; o >>= 1) vals[k] += __shfl_down(vals[k], o, 64);

    __shared__ float red[4][5 + 2*IPB];
    int wave = t >> 6, lane = t & 63;
    if (lane == 0) {
        #pragma unroll
        for (int k = 0; k < 5 + 2*IPB; k++) red[wave][k] = vals[k];
    }
    __syncthreads();
    if (t == 0) {
        float v[5 + 2*IPB];
        #pragma unroll
        for (int k = 0; k < 5 + 2*IPB; k++)
            v[k] = red[0][k] + red[1][k] + red[2][k] + red[3][k];
        float* p = part + (((size_t)l * (N / IPB) + ib) * JSPLIT + js) * 8;
        p[0]=v[0]; p[1]=v[1]; p[2]=v[2]; p[3]=v[3]; p[4]=v[4];
        if (last) {
            #pragma unroll
            for (int q = 0; q < IPB; q++) {
                lddt_ls[(size_t)js * N + i0 + q] = v[5+2*q];
                lddt_lc[(size_t)js * N + i0 + q] = v[6+2*q];
            }
        }
    }
}

// ---------------- reduce: sum per-block partials -> scalars + lddt ----------------
__global__ __launch_bounds__(256) void reduce_kernel(
    const int* __restrict__ packed, const float* __restrict__ part,
    const float* __restrict__ lddt_ls, const float* __restrict__ lddt_lc,
    float* __restrict__ out, float* __restrict__ out_lddt, int L, int N)
{
    int t = threadIdx.x;
    int BPL = (N / IPB) * JSPLIT;
    float ss[4]={0,0,0,0}, so[4]={0,0,0,0}, rt[4]={0,0,0,0};
    float cs=0.f, co=0.f;
    for (int b = t; b < BPL * L; b += 256) {
        int l = b / BPL;
        const float* p = part + (size_t)b * 8;
        ss[l] += p[0]; so[l] += p[1]; rt[l] += p[4];
        if (l == 0) { cs += p[2]; co += p[3]; }
    }
    float nr = 0.f;
    for (int i = t; i < N; i += 256)
        nr += ((packed[i] & 0xFFFF) != 0) ? 1.f : 0.f;

    // lddt finalize (independent per i)
    for (int i = t; i < N; i += 256) {
        float s = 0.f, c = 0.f;
        #pragma unroll
        for (int js = 0; js < JSPLIT; js++) {
            s += lddt_ls[(size_t)js * N + i];
            c += lddt_lc[(size_t)js * N + i];
        }
        out_lddt[i] = s / fmaxf(c, 1e-6f);
    }

    __shared__ float red[4];
    int wave = t >> 6, lane = t & 63;
    float vals[11];
    vals[0]=cs; vals[1]=co; vals[2]=nr;
    for (int l = 0; l < L; l++) { vals[3+l]=ss[l]; vals[3+L+l]=so[l]; vals[3+2*L+l]=rt[l]; }
    float res[11];
    for (int k = 0; k < 3 + 3*L; k++) {
        float v = vals[k];
        for (int o = 32; o > 0; o >>= 1) v += __shfl_down(v, o, 64);
        __syncthreads();
        if (lane == 0) red[wave] = v;
        __syncthreads();
        res[k] = red[0] + red[1] + red[2] + red[3];
    }
    if (t == 0) {
        float csf = fmaxf(res[0], 1e-6f);
        float cof = fmaxf(res[1], 1e-6f);
        float nrm = fmaxf(res[2], 1e-6f);
        for (int l = 0; l < L; l++) {
            out[l]     = res[3+l] / csf / 10.f + res[3+L+l] / cof / 10.f;
            out[L + l] = res[3+2*L+l] / nrm;
        }
    }
}

extern "C" void kernel_launch(void* const* d_in, const int* in_sizes, int n_in,
                              void* d_out, int out_size, void* d_ws, size_t ws_size,
                              hipStream_t stream)
{
    const float* pred      = (const float*)d_in[0];
    const float* gt        = (const float*)d_in[1];
    const float* atom_mask = (const float*)d_in[2];
    const int*   batch     = (const int*)d_in[3];
    const int*   chain     = (const int*)d_in[4];

    int N = in_sizes[3];
    int A = in_sizes[2] / N;
    int L = in_sizes[0] / (N * A * 3);

    float* out = (float*)d_out;
    float* out_final = out + 2 * L;
    float* out_rot   = out_final + (size_t)N * N;
    float* out_lddt  = out_rot + N;

    float* ws = (float*)d_ws;
    float* Mc      = ws;                                  // L*N*12
    float* gtca    = Mc + (size_t)L * N * 12;             // N*3
    float* predca  = gtca + (size_t)N * 3;                // N*3
    float* part    = predca + (size_t)N * 3;              // L*(N/IPB)*JSPLIT*8
    float* lddt_ls = part + (size_t)L * (N / IPB) * JSPLIT * 8;  // JSPLIT*N
    float* lddt_lc = lddt_ls + (size_t)JSPLIT * N;        // JSPLIT*N
    float4* predT4 = (float4*)(lddt_lc + (size_t)JSPLIT * N);    // L*A*N float4
    float4* gtT4   = predT4 + (size_t)L * A * N;          // A*N float4
    int*   packed  = (int*)(gtT4 + (size_t)A * N);        // N

    int totalT = (L + 1) * A * N;
    prep_all_kernel<<<(totalT + 255) / 256, 256, 0, stream>>>(
        pred, gt, atom_mask, batch, chain,
        Mc, packed, gtca, predca, predT4, gtT4, L, N, A);

    dim3 grid(N / IPB, JSPLIT, L);   // 192 x 3 x 2 = 1152 blocks
    fape_kernel<<<grid, 256, 0, stream>>>(
        predT4, gtT4, Mc, packed, gtca, predca, part, lddt_ls, lddt_lc,
        out_final, out_rot, out_lddt, L, N);

    reduce_kernel<<<1, 256, 0, stream>>>(packed, part, lddt_ls, lddt_lc,
                                         out, out_lddt, L, N);
}

// Round 12
// 87.402 us; speedup vs baseline: 1.1043x; 1.0926x over previous
//
#include <hip/hip_runtime.h>
#include <math.h>

#define EPS 1e-6f
#define IPB 2    // i per block

struct F3 { float x, y, z; };
__device__ inline F3 sub3(F3 a, F3 b){return {a.x-b.x,a.y-b.y,a.z-b.z};}
__device__ inline float dot3(F3 a, F3 b){return a.x*b.x+a.y*b.y+a.z*b.z;}
__device__ inline F3 scale3(F3 a,float s){return {a.x*s,a.y*s,a.z*s};}
__device__ inline F3 cross3(F3 a,F3 b){return {a.y*b.z-a.z*b.y, a.z*b.x-a.x*b.z, a.x*b.y-a.y*b.x};}
__device__ inline F3 norm3(F3 v){float s=dot3(v,v);float inv=1.f/sqrtf(fmaxf(s,EPS));return scale3(v,inv);}

__device__ inline void make_frame(const float* __restrict__ base, float R[9], F3& ca) {
    F3 n = {base[0], base[1], base[2]};
    ca   = {base[3], base[4], base[5]};
    F3 c = {base[6], base[7], base[8]};
    F3 e1 = norm3(sub3(c, ca));
    F3 v2 = sub3(n, ca);
    float d = dot3(e1, v2);
    F3 e2 = norm3({v2.x - d*e1.x, v2.y - d*e1.y, v2.z - d*e1.z});
    F3 e3 = cross3(e1, e2);
    R[0]=e1.x; R[1]=e1.y; R[2]=e1.z;
    R[3]=e2.x; R[4]=e2.y; R[5]=e2.z;
    R[6]=e3.x; R[7]=e3.y; R[8]=e3.z;
}

// ---------------- prep + transpose fused ----------------
__global__ __launch_bounds__(256) void prep_all_kernel(
    const float* __restrict__ pred, const float* __restrict__ gt,
    const float* __restrict__ atom_mask, const int* __restrict__ batch,
    const int* __restrict__ chain,
    float* __restrict__ Mc, int* __restrict__ packed,
    float* __restrict__ gtca, float* __restrict__ predca,
    float4* __restrict__ predT4, float4* __restrict__ gtT4,
    int L, int N, int A)
{
    int idx = blockIdx.x * blockDim.x + threadIdx.x;

    // ---- transpose part: float4 slabs [a][j] ----
    int totalT = (L + 1) * A * N;
    if (idx < totalT) {
        int z = idx / (A * N);
        int r = idx - z * (A * N);
        int a = r / N;
        int j = r - a * N;
        if (z < L) {
            const float* s = pred + (((size_t)z * N + j) * A + a) * 3;
            predT4[((size_t)z * A + a) * N + j] = make_float4(s[0], s[1], s[2], 0.f);
        } else {
            const float* s = gt + ((size_t)j * A + a) * 3;
            gtT4[(size_t)a * N + j] = make_float4(s[0], s[1], s[2], 0.f);
        }
    }

    // ---- prep part ----
    if (idx >= L * N) return;
    int l = idx / N, i = idx - l * N;

    float Rg[9]; F3 cag;
    make_frame(gt + (size_t)i * A * 3, Rg, cag);
    float Rp[9]; F3 cap;
    make_frame(pred + ((size_t)l * N + i) * A * 3, Rp, cap);

    // |Rp^T(x-tp) - Rg^T(y-tg)| == |x - (M y + c)|, M = Rp Rg^T, c = tp - M tg
    float m[9];
    #pragma unroll
    for (int d = 0; d < 3; d++)
        #pragma unroll
        for (int e = 0; e < 3; e++)
            m[d*3+e] = Rp[0*3+d]*Rg[0*3+e] + Rp[1*3+d]*Rg[1*3+e] + Rp[2*3+d]*Rg[2*3+e];
    float c0 = cap.x - (m[0]*cag.x + m[1]*cag.y + m[2]*cag.z);
    float c1 = cap.y - (m[3]*cag.x + m[4]*cag.y + m[5]*cag.z);
    float c2 = cap.z - (m[6]*cag.x + m[7]*cag.y + m[8]*cag.z);

    float* o = Mc + (size_t)idx * 12;
    #pragma unroll
    for (int k = 0; k < 9; k++) o[k] = m[k];
    o[9] = c0; o[10] = c1; o[11] = c2;

    if (l == 0) {
        unsigned mm = 0;
        for (int a = 0; a < A; a++)
            if (atom_mask[(size_t)i * A + a] > 0.f) mm |= (1u << a);
        packed[i] = (int)(mm | ((unsigned)batch[i] << 16) | ((unsigned)chain[i] << 24));
        gtca[i*3] = cag.x; gtca[i*3+1] = cag.y; gtca[i*3+2] = cag.z;
    }
    if (l == L - 1) { predca[i*3] = cap.x; predca[i*3+1] = cap.y; predca[i*3+2] = cap.z; }
}

// ---------------- fape: block = (l, i-pair), lanes stride j; float4 SoA loads ----
__global__ __launch_bounds__(256) void fape_kernel(
    const float4* __restrict__ predT4, const float4* __restrict__ gtT4,
    const float* __restrict__ Mc, const int* __restrict__ packed,
    const float* __restrict__ gtca, const float* __restrict__ predca,
    float* __restrict__ part,
    float* __restrict__ out_final, float* __restrict__ out_rot,
    float* __restrict__ out_lddt,
    int L, int N)
{
    int t = threadIdx.x;
    int ib = blockIdx.x, l = blockIdx.y;
    int i0 = ib * IPB;
    int i1 = i0 + 1;
    bool last = (l == L - 1);

    // block-uniform -> scalar loads
    const float* __restrict__ mcp = Mc + ((size_t)l * N + i0) * 12;
    float A00=mcp[0],A01=mcp[1],A02=mcp[2],A10=mcp[3],A11=mcp[4],A12=mcp[5],
          A20=mcp[6],A21=mcp[7],A22=mcp[8],Ac0=mcp[9],Ac1=mcp[10],Ac2=mcp[11];
    float B00=mcp[12],B01=mcp[13],B02=mcp[14],B10=mcp[15],B11=mcp[16],B12=mcp[17],
          B20=mcp[18],B21=mcp[19],B22=mcp[20],Bc0=mcp[21],Bc1=mcp[22],Bc2=mcp[23];
    int pk0 = packed[i0], pk1 = packed[i1];
    int msk0 = pk0 & 0xFFFF, bat0 = (pk0 >> 16) & 0xFF, ch0 = (pk0 >> 24) & 0xFF;
    int msk1 = pk1 & 0xFFFF, bat1 = (pk1 >> 16) & 0xFF, ch1 = (pk1 >> 24) & 0xFF;

    float g0x=0,g0y=0,g0z=0,p0x=0,p0y=0,p0z=0;
    float g1x=0,g1y=0,g1z=0,p1x=0,p1y=0,p1z=0;
    if (last) {
        g0x=gtca[i0*3]; g0y=gtca[i0*3+1]; g0z=gtca[i0*3+2];
        p0x=predca[i0*3]; p0y=predca[i0*3+1]; p0z=predca[i0*3+2];
        g1x=gtca[i1*3]; g1y=gtca[i1*3+1]; g1z=gtca[i1*3+2];
        p1x=predca[i1*3]; p1y=predca[i1*3+1]; p1z=predca[i1*3+2];
    }

    const float4* __restrict__ xT4 = predT4 + (size_t)l * 14 * N;   // [a][j]

    float a_ss=0.f, a_so=0.f, a_cs=0.f, a_co=0.f, a_rot=0.f;
    float ls0=0.f, lc0=0.f, ls1=0.f, lc1=0.f;

    for (int j = t; j < N; j += 256) {
        int pkj = packed[j];
        int mskj = pkj & 0xFFFF;
        int bj = (pkj >> 16) & 0xFF, cj = (pkj >> 24) & 0xFF;

        int mj0 = msk0 & mskj, mj1 = msk1 & mskj;
        bool pm0 = (bj == bat0) && (mj0 != 0);
        bool pm1 = (bj == bat1) && (mj1 != 0);
        float num0 = 0.f, num1 = 0.f;

        if (__any(pm0 || pm1)) {
            #pragma unroll
            for (int a = 0; a < 14; a++) {
                float4 Y = gtT4[(size_t)a * N + j];   // coalesced dwordx4
                float4 X = xT4[(size_t)a * N + j];
                float d0 = X.x - (A00*Y.x + A01*Y.y + A02*Y.z + Ac0);
                float d1 = X.y - (A10*Y.x + A11*Y.y + A12*Y.z + Ac1);
                float d2 = X.z - (A20*Y.x + A21*Y.y + A22*Y.z + Ac2);
                num0 += (float)((mj0 >> a) & 1) * sqrtf(fmaxf(d0*d0+d1*d1+d2*d2, EPS));
                float e0 = X.x - (B00*Y.x + B01*Y.y + B02*Y.z + Bc0);
                float e1 = X.y - (B10*Y.x + B11*Y.y + B12*Y.z + Bc1);
                float e2 = X.z - (B20*Y.x + B21*Y.y + B22*Y.z + Bc2);
                num1 += (float)((mj1 >> a) & 1) * sqrtf(fmaxf(e0*e0+e1*e1+e2*e2, EPS));
            }
        }

        float fv0 = pm0 ? num0 / (float)__popc((unsigned)mj0) : 0.f;
        float fv1 = pm1 ? num1 / (float)__popc((unsigned)mj1) : 0.f;

        if (last) {
            out_final[(size_t)i0 * N + j] = fv0;   // coalesced
            out_final[(size_t)i1 * N + j] = fv1;
            if (j == i0) out_rot[i0] = fv0;
            if (j == i1) out_rot[i1] = fv1;
        }
        if (j == i0) a_rot += fv0;
        if (j == i1) a_rot += fv1;
        if (pm0) {
            float cl = fminf(fv0, 10.f);
            if (ch0 == cj) { a_ss += cl; a_cs += 1.f; } else { a_so += cl; a_co += 1.f; }
        }
        if (pm1) {
            float cl = fminf(fv1, 10.f);
            if (ch1 == cj) { a_ss += cl; a_cs += 1.f; } else { a_so += cl; a_co += 1.f; }
        }
        if (last) {
            float4 CG = gtT4[(size_t)1 * N + j];   // CA of row j (atom 1)
            float4 CP = xT4[(size_t)1 * N + j];
            bool ok0 = (msk0 != 0) && (mskj != 0) && (j != i0);
            bool ok1 = (msk1 != 0) && (mskj != 0) && (j != i1);
            if (ok0) {
                float dx=g0x-CG.x, dy=g0y-CG.y, dz=g0z-CG.z;
                float gd = sqrtf(fmaxf(dx*dx+dy*dy+dz*dz, EPS));
                if (gd < 15.f) {
                    float ex=p0x-CP.x, ey=p0y-CP.y, ez=p0z-CP.z;
                    float pd = sqrtf(fmaxf(ex*ex+ey*ey+ez*ez, EPS));
                    float de = fabsf(gd - pd);
                    ls0 += ((de<0.5f?1.f:0.f)+(de<1.f?1.f:0.f)+(de<2.f?1.f:0.f)+(de<4.f?1.f:0.f))*0.25f;
                    lc0 += 1.f;
                }
            }
            if (ok1) {
                float dx=g1x-CG.x, dy=g1y-CG.y, dz=g1z-CG.z;
                float gd = sqrtf(fmaxf(dx*dx+dy*dy+dz*dz, EPS));
                if (gd < 15.f) {
                    float ex=p1x-CP.x, ey=p1y-CP.y, ez=p1z-CP.z;
                    float pd = sqrtf(fmaxf(ex*ex+ey*ey+ez*ez, EPS));
                    float de = fabsf(gd - pd);
                    ls1 += ((de<0.5f?1.f:0.f)+(de<1.f?1.f:0.f)+(de<2.f?1.f:0.f)+(de<4.f?1.f:0.f))*0.25f;
                    lc1 += 1.f;
                }
            }
        }
    }

    // ---- block-local reduction of 9 values (no global atomics) ----
    for (int o = 32; o > 0; o >>= 1) {
        a_ss += __shfl_down(a_ss, o, 64);  a_so += __shfl_down(a_so, o, 64);
        a_cs += __shfl_down(a_cs, o, 64);  a_co += __shfl_down(a_co, o, 64);
        a_rot += __shfl_down(a_rot, o, 64);
        ls0 += __shfl_down(ls0, o, 64);    lc0 += __shfl_down(lc0, o, 64);
        ls1 += __shfl_down(ls1, o, 64);    lc1 += __shfl_down(lc1, o, 64);
    }
    __shared__ float red[4][9];
    int wave = t >> 6, lane = t & 63;
    if (lane == 0) {
        red[wave][0]=a_ss; red[wave][1]=a_so; red[wave][2]=a_cs; red[wave][3]=a_co;
        red[wave][4]=a_rot; red[wave][5]=ls0; red[wave][6]=lc0; red[wave][7]=ls1; red[wave][8]=lc1;
    }
    __syncthreads();
    if (t == 0) {
        float v[9];
        #pragma unroll
        for (int k = 0; k < 9; k++)
            v[k] = red[0][k] + red[1][k] + red[2][k] + red[3][k];
        float* p = part + ((size_t)l * (N / IPB) + ib) * 8;
        p[0]=v[0]; p[1]=v[1]; p[2]=v[2]; p[3]=v[3]; p[4]=v[4];
        if (last) {
            out_lddt[i0] = v[5] / fmaxf(v[6], 1e-6f);
            out_lddt[i1] = v[7] / fmaxf(v[8], 1e-6f);
        }
    }
}

// ---------------- reduce: sum per-block partials -> scalars ----------------
__global__ __launch_bounds__(256) void reduce_kernel(
    const int* __restrict__ packed, const float* __restrict__ part,
    float* __restrict__ out, int L, int N)
{
    int t = threadIdx.x;
    int BPL = N / IPB;
    float ss[4]={0,0,0,0}, so[4]={0,0,0,0}, rt[4]={0,0,0,0};
    float cs=0.f, co=0.f;
    for (int b = t; b < BPL * L; b += 256) {
        int l = b / BPL;
        const float* p = part + (size_t)b * 8;
        ss[l] += p[0]; so[l] += p[1]; rt[l] += p[4];
        if (l == 0) { cs += p[2]; co += p[3]; }
    }
    float nr = 0.f;
    for (int i = t; i < N; i += 256)
        nr += ((packed[i] & 0xFFFF) != 0) ? 1.f : 0.f;

    __shared__ float red[4];
    int wave = t >> 6, lane = t & 63;
    float vals[11];
    vals[0]=cs; vals[1]=co; vals[2]=nr;
    for (int l = 0; l < L; l++) { vals[3+l]=ss[l]; vals[3+L+l]=so[l]; vals[3+2*L+l]=rt[l]; }
    float res[11];
    for (int k = 0; k < 3 + 3*L; k++) {
        float v = vals[k];
        for (int o = 32; o > 0; o >>= 1) v += __shfl_down(v, o, 64);
        __syncthreads();
        if (lane == 0) red[wave] = v;
        __syncthreads();
        res[k] = red[0] + red[1] + red[2] + red[3];
    }
    if (t == 0) {
        float csf = fmaxf(res[0], 1e-6f);
        float cof = fmaxf(res[1], 1e-6f);
        float nrm = fmaxf(res[2], 1e-6f);
        for (int l = 0; l < L; l++) {
            out[l]     = res[3+l] / csf / 10.f + res[3+L+l] / cof / 10.f;
            out[L + l] = res[3+2*L+l] / nrm;
        }
    }
}

extern "C" void kernel_launch(void* const* d_in, const int* in_sizes, int n_in,
                              void* d_out, int out_size, void* d_ws, size_t ws_size,
                              hipStream_t stream)
{
    const float* pred      = (const float*)d_in[0];
    const float* gt        = (const float*)d_in[1];
    const float* atom_mask = (const float*)d_in[2];
    const int*   batch     = (const int*)d_in[3];
    const int*   chain     = (const int*)d_in[4];

    int N = in_sizes[3];
    int A = in_sizes[2] / N;
    int L = in_sizes[0] / (N * A * 3);

    float* out = (float*)d_out;
    float* out_final = out + 2 * L;
    float* out_rot   = out_final + (size_t)N * N;
    float* out_lddt  = out_rot + N;

    float* ws = (float*)d_ws;
    float* Mc      = ws;                                  // L*N*12
    float* gtca    = Mc + (size_t)L * N * 12;             // N*3
    float* predca  = gtca + (size_t)N * 3;                // N*3
    float* part    = predca + (size_t)N * 3;              // (L*N/IPB)*8
    float4* predT4 = (float4*)(part + (size_t)L * (N / IPB) * 8);  // L*A*N float4
    float4* gtT4   = predT4 + (size_t)L * A * N;          // A*N float4
    int*   packed  = (int*)(gtT4 + (size_t)A * N);        // N

    int totalT = (L + 1) * A * N;
    prep_all_kernel<<<(totalT + 255) / 256, 256, 0, stream>>>(
        pred, gt, atom_mask, batch, chain,
        Mc, packed, gtca, predca, predT4, gtT4, L, N, A);

    dim3 grid(N / IPB, L);   // 384 x 2 = 768 blocks
    fape_kernel<<<grid, 256, 0, stream>>>(
        predT4, gtT4, Mc, packed, gtca, predca, part,
        out_final, out_rot, out_lddt, L, N);

    reduce_kernel<<<1, 256, 0, stream>>>(packed, part, out, L, N);
}